// Round 18
// baseline (242.460 us; speedup 1.0000x reference)
//
#include <hip/hip_runtime.h>
#include <hip/hip_bf16.h>
#include <stdint.h>

typedef __hip_bfloat16 bf16;
typedef __attribute__((ext_vector_type(8))) short short8;
typedef __attribute__((ext_vector_type(4))) float f32x4;

__device__ __forceinline__ bf16 f2b(float v){ return __float2bfloat16(v); }
__device__ __forceinline__ short s2s(float v){ bf16 b = __float2bfloat16(v); return *reinterpret_cast<short*>(&b); }
__device__ __forceinline__ short8 s8zero()
{
    short8 z;
    for (int i = 0; i < 8; ++i) z[i] = 0;
    return z;
}

// ============ ONE fused weight-prep kernel (9 transforms, segment if-chain) ============
__global__ void prep_weights(const float* __restrict__ ew1, const float* __restrict__ ew2,
                             const float* __restrict__ ew3, const float* __restrict__ dw1,
                             const float* __restrict__ dw2, const float* __restrict__ dw3,
                             const float* __restrict__ kw,  const float* __restrict__ f1w,
                             const float* __restrict__ f2w,
                             bf16* __restrict__ wte1, bf16* __restrict__ wte2,
                             bf16* __restrict__ wte3, bf16* __restrict__ wtb4,
                             bf16* __restrict__ wtb5, bf16* __restrict__ wtb6,
                             bf16* __restrict__ kwt,  bf16* __restrict__ wtf1,
                             bf16* __restrict__ wtf2)
{
    int idx = blockIdx.x * blockDim.x + threadIdx.x;
    if (idx < 1536) {
        int q = idx >> 9, r = idx & 511;
        int co = r >> 5, k = r & 31;
        int j = k >> 3, ci = k & 7;
        int t = 4 * q + j;
        float v = (ci < 3 && t < 9) ? ew1[((size_t)co * 3 + ci) * 9 + t] : 0.f;
        wte1[idx] = f2b(v);
        return;
    }
    idx -= 1536;
    if (idx < 5120) {
        int p = idx >> 10, r = idx & 1023;
        int co = r >> 5, k = r & 31;
        int t = 2 * p + (k >> 4);
        int ch = k & 15;
        float v = (t <= 8) ? ew2[((size_t)co * 16 + ch) * 9 + t] : 0.f;
        wte2[idx] = f2b(v);
        return;
    }
    idx -= 5120;
    if (idx < 18432) {
        int co = idx / 288;
        int r  = idx - co * 288;
        int ci = r / 9, t = r - ci * 9;
        wte3[((size_t)t * 64 + co) * 32 + ci] = f2b(ew3[idx]);
        return;
    }
    idx -= 18432;
    if (idx < 36864) {
        int ci = idx / 576;
        int r  = idx - ci * 576;
        int co = r / 9, t = r - co * 9;
        wtb4[((size_t)t * 64 + co) * 64 + ci] = f2b(dw1[idx]);
        return;
    }
    idx -= 36864;
    if (idx < 18432) {
        int ci = idx / 288;
        int r  = idx - ci * 288;
        int co = r / 9, t = r - co * 9;
        wtb5[((size_t)t * 32 + co) * 64 + ci] = f2b(dw2[idx]);
        return;
    }
    idx -= 18432;
    if (idx < 4608) {
        int ci = idx / 144;
        int r  = idx - ci * 144;
        int co = r / 9, t = r - co * 9;
        wtb6[((size_t)t * 16 + co) * 32 + ci] = f2b(dw3[idx]);
        return;
    }
    idx -= 4608;
    if (idx < 458752) {
        int e = idx >> 12, kk = idx & 4095;
        int pos = kk >> 6, ci = kk & 63;
        float v = (e < 110) ? kw[(size_t)e * 4096 + ci * 64 + pos] : 0.f;
        kwt[idx] = f2b(v);
        return;
    }
    idx -= 458752;
    if (idx < 655360) {
        int n = idx / 1280, k = idx - n * 1280;
        float v = (k < 1210) ? f1w[(size_t)n * 1210 + k] : 0.f;
        wtf1[idx] = f2b(v);
        return;
    }
    idx -= 655360;
    if (idx < 131072) {
        wtf2[idx] = f2b(f2w[idx]);
        return;
    }
}

// ============ FUSED encoder (512 threads, 8 waves): x fp32 -> LDS -> h3b bf16 NHWC ============
__global__ __launch_bounds__(512)
void enc123_fused(const float* __restrict__ xg,
                  const bf16* __restrict__ wte1, const float* __restrict__ eb1,
                  const bf16* __restrict__ wte2, const float* __restrict__ eb2,
                  const bf16* __restrict__ wte3, const float* __restrict__ eb3,
                  bf16* __restrict__ h3g)
{
    __shared__ char smem[57728];
    short8* H1  = (short8*)smem;             // 2312 short8
    short8* Xs1 = (short8*)(smem + 36992);   // 1156 short8
    short8* H2  = (short8*)(smem + 36992);   // 1296 short8 — overlays Xs1

    const int img = blockIdx.x;
    const int tid = threadIdx.x;
    const float* xi = xg + (size_t)img * 3072;

    for (int e = tid; e < 1156; e += 512) {
        int hr = e / 34, wc = e % 34;
        int hi = hr - 1, wi = wc - 1;
        short8 v = s8zero();
        if ((unsigned)hi < 32u && (unsigned)wi < 32u) {
            int p = hi * 32 + wi;
            v[0] = s2s(xi[p]);
            v[1] = s2s(xi[p + 1024]);
            v[2] = s2s(xi[p + 2048]);
        }
        Xs1[e] = v;
    }
    for (int e = tid; e < 264; e += 512) {
        int c8 = e & 1, q = e >> 1;
        int pl = q / 33, j = q % 33;
        int pos = (j < 17) ? j : (j - 16) * 17;
        H1[(pl * 289 + pos) * 2 + c8] = s8zero();
    }
    __syncthreads();

    const int wv = tid >> 6, lane = tid & 63;
    const int lp = lane & 15, lq = lane >> 4;

    // ---- enc1: 8 waves x 8 m-tiles ----
    {
        short8 wf[3];
        #pragma unroll
        for (int q = 0; q < 3; ++q)
            wf[q] = *reinterpret_cast<const short8*>(wte1 + (size_t)(q * 16 + lp) * 32 + lq * 8);
        float bv[4];
        #pragma unroll
        for (int r = 0; r < 4; ++r) bv[r] = eb1[lq * 4 + r];

        for (int mt = wv * 8; mt < wv * 8 + 8; ++mt) {
            int m = mt * 16 + lp;
            int ho = m >> 5, wo = m & 31;
            f32x4 acc = {0.f, 0.f, 0.f, 0.f};
            #pragma unroll
            for (int q = 0; q < 3; ++q) {
                int t = 4 * q + lq;
                if (t > 8) t = 8;
                int pos = (ho + t / 3) * 34 + (wo + t % 3);
                acc = __builtin_amdgcn_mfma_f32_16x16x32_bf16(wf[q], Xs1[pos], acc, 0, 0, 0);
            }
            int pl  = (ho & 1) * 2 + (wo & 1);
            int pos = ((ho >> 1) + 1) * 17 + ((wo >> 1) + 1);
            int slot = (pl * 289 + pos) * 2 + ((lq >> 1) ^ (pos & 1));
            __align__(8) bf16 ov[4];
            #pragma unroll
            for (int r = 0; r < 4; ++r) ov[r] = f2b(fmaxf(acc[r] + bv[r], 0.f));
            *reinterpret_cast<uint2*>(reinterpret_cast<char*>(&H1[slot]) + (lq & 1) * 8)
                = *reinterpret_cast<uint2*>(ov);
        }
    }
    __syncthreads();

    for (int e = tid; e < 272; e += 512) {
        int c8 = e & 3, q = e >> 2;
        int pl = q / 17, j = q % 17;
        int pos = (j < 9) ? j : (j - 8) * 9;
        H2[(pl * 81 + pos) * 4 + c8] = s8zero();
    }
    // ---- enc2: 2 nt x 4 row-groups x 4 m-tiles ----
    {
        const int nt = wv & 1, mh = wv >> 1;
        short8 wf[5];
        #pragma unroll
        for (int p = 0; p < 5; ++p)
            wf[p] = *reinterpret_cast<const short8*>(wte2 + ((size_t)(p * 32 + nt * 16 + lp)) * 32 + lq * 8);
        float bv[4];
        #pragma unroll
        for (int r = 0; r < 4; ++r) bv[r] = eb2[nt * 16 + lq * 4 + r];

        for (int mt = mh * 4; mt < mh * 4 + 4; ++mt) {
            int m = mt * 16 + lp;
            int ho = m >> 4, wo = m & 15;
            f32x4 acc = {0.f, 0.f, 0.f, 0.f};
            #pragma unroll
            for (int p = 0; p < 5; ++p) {
                const int tA = 2 * p, tB = (p < 4) ? 2 * p + 1 : 8;
                const int khA = tA / 3, kwA = tA % 3;
                const int paA = (khA == 1) ? 0 : 1, dhA = (khA == 0) ? -1 : 0;
                const int pbA = (kwA == 1) ? 0 : 1, dwA = (kwA == 0) ? -1 : 0;
                const int khB = tB / 3, kwB = tB % 3;
                const int paB = (khB == 1) ? 0 : 1, dhB = (khB == 0) ? -1 : 0;
                const int pbB = (kwB == 1) ? 0 : 1, dwB = (kwB == 0) ? -1 : 0;
                int posA = (ho + dhA + 1) * 17 + (wo + dwA + 1);
                int posB = (ho + dhB + 1) * 17 + (wo + dwB + 1);
                int idxA = ((paA * 2 + pbA) * 289 + posA) * 2 + ((lq & 1) ^ (posA & 1));
                int idxB = ((paB * 2 + pbB) * 289 + posB) * 2 + ((lq & 1) ^ (posB & 1));
                short8 b = H1[(lq < 2) ? idxA : idxB];
                acc = __builtin_amdgcn_mfma_f32_16x16x32_bf16(wf[p], b, acc, 0, 0, 0);
            }
            int pl  = (ho & 1) * 2 + (wo & 1);
            int pos = ((ho >> 1) + 1) * 9 + ((wo >> 1) + 1);
            int c8w = nt * 2 + (lq >> 1);
            int slot = (pl * 81 + pos) * 4 + (c8w ^ (pos & 3));
            __align__(8) bf16 ov[4];
            #pragma unroll
            for (int r = 0; r < 4; ++r) ov[r] = f2b(fmaxf(acc[r] + bv[r], 0.f));
            *reinterpret_cast<uint2*>(reinterpret_cast<char*>(&H2[slot]) + (lq & 1) * 8)
                = *reinterpret_cast<uint2*>(ov);
        }
    }
    __syncthreads();

    // ---- enc3: 4 nt x 2 m-tiles per wave ----
    {
        const int nt = wv & 3, mh = wv >> 2;
        short8 wf[9];
        #pragma unroll
        for (int t = 0; t < 9; ++t)
            wf[t] = *reinterpret_cast<const short8*>(wte3 + ((size_t)(t * 64 + nt * 16 + lp)) * 32 + lq * 8);
        float bv[4];
        #pragma unroll
        for (int r = 0; r < 4; ++r) bv[r] = eb3[nt * 16 + lq * 4 + r];

        bf16* yi = h3g + (size_t)img * 4096;
        for (int mt = mh * 2; mt < mh * 2 + 2; ++mt) {
            int m = mt * 16 + lp;
            int ho = m >> 3, wo = m & 7;
            f32x4 acc = {0.f, 0.f, 0.f, 0.f};
            #pragma unroll
            for (int t = 0; t < 9; ++t) {
                const int kh = t / 3, kw2 = t % 3;
                const int pa = (kh == 1) ? 0 : 1, dh = (kh == 0) ? -1 : 0;
                const int pb = (kw2 == 1) ? 0 : 1, dw = (kw2 == 0) ? -1 : 0;
                int pos = (ho + dh + 1) * 9 + (wo + dw + 1);
                int idx = ((pa * 2 + pb) * 81 + pos) * 4 + (lq ^ (pos & 3));
                acc = __builtin_amdgcn_mfma_f32_16x16x32_bf16(wf[t], H2[idx], acc, 0, 0, 0);
            }
            __align__(8) bf16 ov[4];
            #pragma unroll
            for (int r = 0; r < 4; ++r) ov[r] = f2b(fmaxf(acc[r] + bv[r], 0.f));
            *reinterpret_cast<uint2*>(yi + ((size_t)(ho * 8 + wo)) * 64 + nt * 16 + lq * 4)
                = *reinterpret_cast<uint2*>(ov);
        }
    }
}

// ============ FUSED dec1+dec2 (512 threads): h3b -> LDS d1 -> d2p parity layout ============
// d2p per image: [cls 4][nt 2][256 pos][16 ch] bf16
__global__ __launch_bounds__(512)
void dec12_fused(const bf16* __restrict__ h3g,
                 const bf16* __restrict__ wtb4, const float* __restrict__ db1,
                 const bf16* __restrict__ wtb5, const float* __restrict__ db2,
                 bf16* __restrict__ d2p)
{
    __shared__ short8 H3s[648];
    __shared__ short8 D1s[2312];
    const int img = blockIdx.x;
    const int tid = threadIdx.x;
    const bf16* xi = h3g + (size_t)img * 4096;

    for (int e = tid; e < 648; e += 512) {
        int c8 = e & 7, pos = e >> 3;
        int hl = pos / 9, wi = pos % 9;
        short8 v = s8zero();
        if (hl < 8 && wi < 8)
            v = *reinterpret_cast<const short8*>(xi + ((size_t)(hl * 8 + wi)) * 64 + c8 * 8);
        H3s[pos * 8 + (c8 ^ (pos & 7))] = v;
    }
    for (int e = tid; e < 264; e += 512) {
        int c8 = e & 7, q = e >> 3;
        int pos = (q < 17) ? (16 * 17 + q) : ((q - 17) * 17 + 16);
        D1s[pos * 8 + c8] = s8zero();
    }
    __syncthreads();

    const int wv = tid >> 6, lane = tid & 63;
    const int lp = lane & 15, lq = lane >> 4;

    // ---- dec1: 4 nt x (2 waves x 2 m-tiles) ----
    {
        const int nt = wv & 3, mh = wv >> 2;
        short8 wf[9][2];
        #pragma unroll
        for (int t = 0; t < 9; ++t) {
            const bf16* wp = wtb4 + ((size_t)t * 64 + nt * 16 + lp) * 64 + lq * 8;
            wf[t][0] = *reinterpret_cast<const short8*>(wp);
            wf[t][1] = *reinterpret_cast<const short8*>(wp + 32);
        }
        float bv[4];
        #pragma unroll
        for (int r = 0; r < 4; ++r) bv[r] = db1[nt * 16 + lq * 4 + r];

        const int c8w = nt * 2 + (lq >> 1);
        for (int mt = mh * 2; mt < mh * 2 + 2; ++mt) {
            int m = mt * 16 + lp;
            int hq = m >> 3, wq = m & 7;
            f32x4 zero = {0.f, 0.f, 0.f, 0.f};
            f32x4 acc[4] = {zero, zero, zero, zero};
            #pragma unroll
            for (int kh = 0; kh < 3; ++kh) {
                #pragma unroll
                for (int kw = 0; kw < 3; ++kw) {
                    const int pa = (kh + 1) & 1, pb = (kw + 1) & 1;
                    const int oh = (pa + 1 - kh) >> 1, ow = (pb + 1 - kw) >> 1;
                    const int cls = pa * 2 + pb;
                    const int t = kh * 3 + kw;
                    int pos = (hq + oh) * 9 + (wq + ow);
                    int sw = pos & 7;
                    acc[cls] = __builtin_amdgcn_mfma_f32_16x16x32_bf16(wf[t][0], H3s[pos * 8 + (lq ^ sw)], acc[cls], 0, 0, 0);
                    acc[cls] = __builtin_amdgcn_mfma_f32_16x16x32_bf16(wf[t][1], H3s[pos * 8 + ((4 + lq) ^ sw)], acc[cls], 0, 0, 0);
                }
            }
            #pragma unroll
            for (int cls = 0; cls < 4; ++cls) {
                int pa = cls >> 1, pb = cls & 1;
                int ho = hq * 2 + pa, wo = wq * 2 + pb;
                int pos = ho * 17 + wo;
                int slot = pos * 8 + (c8w ^ (pos & 7));
                __align__(8) bf16 ov[4];
                #pragma unroll
                for (int r = 0; r < 4; ++r) ov[r] = f2b(fmaxf(acc[cls][r] + bv[r], 0.f));
                *reinterpret_cast<uint2*>(reinterpret_cast<char*>(&D1s[slot]) + (lq & 1) * 8)
                    = *reinterpret_cast<uint2*>(ov);
            }
        }
    }
    __syncthreads();

    // ---- dec2: 2 nt x 4 row-groups x 4 rows, parity-plane coalesced write ----
    {
        const int nt = wv & 1;
        const int mt0 = (wv >> 1) * 4;
        short8 wf[9][2];
        #pragma unroll
        for (int t = 0; t < 9; ++t) {
            const bf16* wp = wtb5 + ((size_t)t * 32 + nt * 16 + lp) * 64 + lq * 8;
            wf[t][0] = *reinterpret_cast<const short8*>(wp);
            wf[t][1] = *reinterpret_cast<const short8*>(wp + 32);
        }
        float bv[4];
        #pragma unroll
        for (int r = 0; r < 4; ++r) bv[r] = db2[nt * 16 + lq * 4 + r];

        bf16* yo = d2p + (size_t)img * 32768;
        for (int mt = mt0; mt < mt0 + 4; ++mt) {
            const int hq = mt, wq = lp;
            f32x4 zero = {0.f, 0.f, 0.f, 0.f};
            f32x4 acc[4] = {zero, zero, zero, zero};
            #pragma unroll
            for (int kh = 0; kh < 3; ++kh) {
                #pragma unroll
                for (int kw = 0; kw < 3; ++kw) {
                    const int pa = (kh + 1) & 1, pb = (kw + 1) & 1;
                    const int oh = (pa + 1 - kh) >> 1, ow = (pb + 1 - kw) >> 1;
                    const int cls = pa * 2 + pb;
                    const int t = kh * 3 + kw;
                    int pos = (hq + oh) * 17 + (wq + ow);
                    int sw = pos & 7;
                    acc[cls] = __builtin_amdgcn_mfma_f32_16x16x32_bf16(wf[t][0], D1s[pos * 8 + (lq ^ sw)], acc[cls], 0, 0, 0);
                    acc[cls] = __builtin_amdgcn_mfma_f32_16x16x32_bf16(wf[t][1], D1s[pos * 8 + ((4 + lq) ^ sw)], acc[cls], 0, 0, 0);
                }
            }
            #pragma unroll
            for (int cls = 0; cls < 4; ++cls) {
                __align__(8) bf16 ov[4];
                #pragma unroll
                for (int r = 0; r < 4; ++r) ov[r] = f2b(fmaxf(acc[cls][r] + bv[r], 0.f));
                size_t off = (size_t)cls * 8192 + (size_t)nt * 4096 + (hq * 16 + wq) * 16 + lq * 4;
                *reinterpret_cast<uint2*>(yo + off) = *reinterpret_cast<uint2*>(ov);
            }
        }
    }
}

// ============ emb = sigmoid(h3b @ kwt^T + kb); n-tile via blockIdx.y ============
__global__ __launch_bounds__(256)
void emb_mfma(const bf16* __restrict__ h3b, const bf16* __restrict__ kwt,
              const float* __restrict__ kb, float* __restrict__ emb)
{
    __shared__ f32x4 Ls[3][64];
    const int imgbase = blockIdx.x * 16;
    const int nt = blockIdx.y;
    const int w = threadIdx.x >> 6, lane = threadIdx.x & 63;
    const int lp = lane & 15, lq = lane >> 4;
    const int k0 = w * 1024;

    f32x4 acc = {0.f, 0.f, 0.f, 0.f};
    const bf16* bp = h3b + (size_t)(imgbase + lp) * 4096 + k0 + lq * 8;
    const bf16* ap = kwt + (size_t)(nt * 16 + lp) * 4096 + k0 + lq * 8;
    for (int ks = 0; ks < 32; ++ks) {
        short8 bfrag = *reinterpret_cast<const short8*>(bp + ks * 32);
        short8 afrag = *reinterpret_cast<const short8*>(ap + ks * 32);
        acc = __builtin_amdgcn_mfma_f32_16x16x32_bf16(afrag, bfrag, acc, 0, 0, 0);
    }
    if (w > 0) Ls[w - 1][lane] = acc;
    __syncthreads();
    if (w == 0) {
        #pragma unroll
        for (int ww = 0; ww < 3; ++ww) acc += Ls[ww][lane];
        const int e0 = nt * 16 + lq * 4;
        #pragma unroll
        for (int r = 0; r < 4; ++r) {
            int e = e0 + r;
            if (e < 110) {
                float v = acc[r] + kb[e];
                emb[(size_t)(imgbase + lp) * 110 + e] = 1.f / (1.f + expf(-v));
            }
        }
    }
}

// ============ dec3: d2p (parity layout) -> conv_t1 -> fused 1x1 -> dec fp32 NCHW ============
__global__ __launch_bounds__(256)
void convt1_mfma_fused(const bf16* __restrict__ d2p, const bf16* __restrict__ wtb,
                       const float* __restrict__ bias,
                       const float* __restrict__ w4, const float* __restrict__ b4,
                       float* __restrict__ dec)
{
    constexpr int C8 = 4;
    constexpr int HR = 18, WR = 34, NPOS = HR * WR;
    __shared__ short8 Xs[NPOS * C8];

    const int img  = blockIdx.x >> 1;
    const int half = blockIdx.x & 1;
    const int hbase = half * 16;
    const bf16* xi = d2p + (size_t)img * 32768;

    for (int e = threadIdx.x; e < NPOS * C8; e += 256) {
        int c8 = e & 3, pos = e >> 2;
        int hr = pos / WR, wr = pos % WR;
        int hi = hbase - 1 + hr, wi = wr - 1;
        short8 v = s8zero();
        if ((unsigned)hi < 32u && (unsigned)wi < 32u) {
            int cls = ((hi & 1) << 1) | (wi & 1);
            size_t src = (size_t)cls * 8192 + (size_t)(c8 >> 1) * 4096
                       + (((hi >> 1) << 4) + (wi >> 1)) * 16 + (c8 & 1) * 8;
            v = *reinterpret_cast<const short8*>(xi + src);
        }
        Xs[pos * C8 + (c8 ^ (pos & 3))] = v;
    }
    __syncthreads();

    const int wv = threadIdx.x >> 6, lane = threadIdx.x & 63;
    const int lp = lane & 15, lq = lane >> 4;

    short8 wf[9];
    #pragma unroll
    for (int t = 0; t < 9; ++t)
        wf[t] = *reinterpret_cast<const short8*>(wtb + ((size_t)t * 16 + lp) * 32 + lq * 8);
    float bv[4];
    #pragma unroll
    for (int r = 0; r < 4; ++r) bv[r] = bias[lq * 4 + r];
    float w4r[3][4];
    #pragma unroll
    for (int j = 0; j < 3; ++j)
        #pragma unroll
        for (int r = 0; r < 4; ++r) w4r[j][r] = w4[j * 16 + lq * 4 + r];
    float b4r[3] = {b4[0], b4[1], b4[2]};

    for (int mt = wv; mt < 32; mt += 4) {
        int m = mt * 16 + lp;
        int hol = m >> 5, wo = m & 31;
        f32x4 acc = {0.f, 0.f, 0.f, 0.f};
        #pragma unroll
        for (int t = 0; t < 9; ++t) {
            int kh = t / 3, kw = t % 3;
            int pos = (hol + 2 - kh) * WR + (wo + 2 - kw);
            short8 b0 = Xs[pos * C8 + (lq ^ (pos & 3))];
            acc = __builtin_amdgcn_mfma_f32_16x16x32_bf16(wf[t], b0, acc, 0, 0, 0);
        }
        float s0 = 0.f, s1 = 0.f, s2 = 0.f;
        #pragma unroll
        for (int r = 0; r < 4; ++r) {
            float v = fmaxf(acc[r] + bv[r], 0.f);
            s0 += v * w4r[0][r]; s1 += v * w4r[1][r]; s2 += v * w4r[2][r];
        }
        s0 += __shfl_xor(s0, 16); s0 += __shfl_xor(s0, 32);
        s1 += __shfl_xor(s1, 16); s1 += __shfl_xor(s1, 32);
        s2 += __shfl_xor(s2, 16); s2 += __shfl_xor(s2, 32);
        if (lq == 0) {
            int ho = hbase + hol;
            size_t base = (size_t)img * 3072 + ho * 32 + wo;
            dec[base]        = s0 + b4r[0];
            dec[base + 1024] = s1 + b4r[1];
            dec[base + 2048] = s2 + b4r[2];
        }
    }
}

// ============ KDE: 64 blocks -> fdb bf16 [64][1280] (padded) ============
__global__ __launch_bounds__(256)
void kde_kernel(const float* __restrict__ emb, bf16* __restrict__ fdb)
{
    __shared__ float es[3520];
    const int b = blockIdx.x, tid = threadIdx.x;
    for (int i = tid; i < 3520; i += 256) es[i] = emb[(size_t)b * 3520 + i];
    __syncthreads();
    if (tid < 110) {
        float dens[11];
        #pragma unroll
        for (int j = 0; j < 11; ++j) dens[j] = 0.f;
        for (int n = 0; n < 32; ++n) {
            float e = es[n * 110 + tid];
            #pragma unroll
            for (int j = 0; j < 11; ++j) {
                float d = 0.1f * j - e;
                dens[j] += __expf(-50.f * d * d);
            }
        }
        float s = 0.f;
        #pragma unroll
        for (int j = 0; j < 11; ++j) s += dens[j];
        float inv = 1.f / s;
        #pragma unroll
        for (int j = 0; j < 11; ++j)
            fdb[(size_t)b * 1280 + tid * 11 + j] = f2b(dens[j] * inv);
    } else if (tid >= 128 && tid < 198) {
        fdb[(size_t)b * 1280 + 1210 + (tid - 128)] = f2b(0.f);
    }
}

// ============ dense MFMA layer ============
template<int K, int N, int RELU>
__global__ __launch_bounds__(256)
void dense_mfma(const bf16* __restrict__ inb, const bf16* __restrict__ wtb,
                const float* __restrict__ bias, bf16* __restrict__ outb)
{
    __shared__ f32x4 Ls[3][64];
    constexpr int KW = K / 4;
    const int mt = blockIdx.x, nt = blockIdx.y;
    const int w = threadIdx.x >> 6, lane = threadIdx.x & 63;
    const int lp = lane & 15, lq = lane >> 4;
    const int k0 = w * KW;

    f32x4 acc = {0.f, 0.f, 0.f, 0.f};
    const bf16* bp = inb + (size_t)(mt * 16 + lp) * K + k0 + lq * 8;
    const bf16* ap = wtb + (size_t)(nt * 16 + lp) * K + k0 + lq * 8;
    for (int ks = 0; ks < KW / 32; ++ks) {
        short8 bfrag = *reinterpret_cast<const short8*>(bp + ks * 32);
        short8 afrag = *reinterpret_cast<const short8*>(ap + ks * 32);
        acc = __builtin_amdgcn_mfma_f32_16x16x32_bf16(afrag, bfrag, acc, 0, 0, 0);
    }
    if (w > 0) Ls[w - 1][lane] = acc;
    __syncthreads();
    if (w == 0) {
        #pragma unroll
        for (int ww = 0; ww < 3; ++ww) acc += Ls[ww][lane];
        const int b = mt * 16 + lp;
        const int o0 = nt * 16 + lq * 4;
        __align__(8) bf16 ov[4];
        #pragma unroll
        for (int r = 0; r < 4; ++r) {
            float v = acc[r] + bias[o0 + r];
            if (RELU) v = fmaxf(v, 0.f);
            ov[r] = f2b(v);
        }
        *reinterpret_cast<uint2*>(outb + (size_t)b * N + o0) = *reinterpret_cast<uint2*>(ov);
    }
}

// ============ f3: 256 -> 4, one block ============
__global__ __launch_bounds__(256)
void f3_kernel(const bf16* __restrict__ m2b, const float* __restrict__ f3w,
               const float* __restrict__ f3b, float* __restrict__ logits)
{
    __shared__ float m2s[64 * 256];
    const int tid = threadIdx.x;
    for (int i = tid; i < 16384; i += 256) m2s[i] = __bfloat162float(m2b[i]);
    __syncthreads();
    int b = tid >> 2, o = tid & 3;
    float a = f3b[o];
    const float* wr = f3w + o * 256;
    for (int k = 0; k < 256; ++k) a += m2s[b * 256 + k] * wr[k];
    logits[b * 4 + o] = a;
}

extern "C" void kernel_launch(void* const* d_in, const int* in_sizes, int n_in,
                              void* d_out, int out_size, void* d_ws, size_t ws_size,
                              hipStream_t stream)
{
    const float* x    = (const float*)d_in[0];
    const float* ew1  = (const float*)d_in[1];
    const float* eb1  = (const float*)d_in[2];
    const float* ew2  = (const float*)d_in[3];
    const float* eb2  = (const float*)d_in[4];
    const float* ew3  = (const float*)d_in[5];
    const float* eb3  = (const float*)d_in[6];
    const float* kw   = (const float*)d_in[7];
    const float* kb   = (const float*)d_in[8];
    const float* dw1  = (const float*)d_in[9];
    const float* db1  = (const float*)d_in[10];
    const float* dw2  = (const float*)d_in[11];
    const float* db2  = (const float*)d_in[12];
    const float* dw3  = (const float*)d_in[13];
    const float* db3  = (const float*)d_in[14];
    const float* dw4  = (const float*)d_in[15];
    const float* db4  = (const float*)d_in[16];
    const float* f1w  = (const float*)d_in[17];
    const float* f1b  = (const float*)d_in[18];
    const float* f2w  = (const float*)d_in[19];
    const float* f2b_ = (const float*)d_in[20];
    const float* f3w  = (const float*)d_in[21];
    const float* f3b  = (const float*)d_in[22];

    // ---------- workspace ----------
    char* ws = (char*)d_ws;
    float* emb  = (float*)(ws + 0);          //   901,120
    bf16*  fdb  = (bf16*) (ws + 901120);     //   163,840
    bf16*  m1b  = (bf16*) (ws + 1064960);    //    65,536
    bf16*  m2b  = (bf16*) (ws + 1130496);    //    32,768
    bf16*  wte1 = (bf16*) (ws + 1163264);    //     3,072
    bf16*  wte2 = (bf16*) (ws + 1166336);    //    10,240
    bf16*  wte3 = (bf16*) (ws + 1176576);    //    36,864
    bf16*  wtb4 = (bf16*) (ws + 1213440);    //    73,728
    bf16*  wtb5 = (bf16*) (ws + 1287168);    //    36,864
    bf16*  wtb6 = (bf16*) (ws + 1324032);    //     9,216
    bf16*  kwt  = (bf16*) (ws + 1333248);    //   917,504
    bf16*  wtf1 = (bf16*) (ws + 2250752);    // 1,310,720
    bf16*  wtf2 = (bf16*) (ws + 3561472);    //   262,144
    const size_t FIXED = 3823616;

    // per image: h3b 8 KB + d2p 64 KB
    const size_t PER_IMG = 73728;
    int CHUNK = 2048;
    while (CHUNK > 16 && FIXED + (size_t)CHUNK * PER_IMG > ws_size) CHUNK >>= 1;
    const int NCHUNK = 2048 / CHUNK;

    char* p   = ws + FIXED;
    bf16* h3b = (bf16*)(p);
    bf16* d2p = (bf16*)(p + (size_t)CHUNK * 8192);

    float* logits = (float*)d_out;            // 64*4
    float* dec    = (float*)d_out + 256;      // 2048*3*32*32 NCHW

    // ---- fused weight prep (1 launch) ----
    prep_weights<<<(1330176 + 255)/256, 256, 0, stream>>>(
        ew1, ew2, ew3, dw1, dw2, dw3, kw, f1w, f2w,
        wte1, wte2, wte3, wtb4, wtb5, wtb6, kwt, wtf1, wtf2);

    for (int c = 0; c < NCHUNK; ++c) {
        const float* xc   = x   + (size_t)c * CHUNK * 3 * 1024;
        float*       decc = dec + (size_t)c * CHUNK * 3 * 1024;
        float*       embc = emb + (size_t)c * CHUNK * 110;

        enc123_fused<<<CHUNK, 512, 0, stream>>>(xc, wte1, eb1, wte2, eb2, wte3, eb3, h3b);
        emb_mfma<<<dim3(CHUNK/16, 7), 256, 0, stream>>>(h3b, kwt, kb, embc);
        dec12_fused<<<CHUNK, 512, 0, stream>>>(h3b, wtb4, db1, wtb5, db2, d2p);
        convt1_mfma_fused<<<CHUNK*2, 256, 0, stream>>>(d2p, wtb6, db3, dw4, db4, decc);
    }

    // classifier: KDE -> f1 (MFMA) -> f2 (MFMA) -> f3
    kde_kernel<<<64, 256, 0, stream>>>(emb, fdb);
    dense_mfma<1280, 512, 1><<<dim3(4, 32), 256, 0, stream>>>(fdb, wtf1, f1b, m1b);
    dense_mfma<512, 256, 1> <<<dim3(4, 16), 256, 0, stream>>>(m1b, wtf2, f2b_, m2b);
    f3_kernel<<<1, 256, 0, stream>>>(m2b, f3w, f3b, logits);
}

// Round 19
// 238.916 us; speedup vs baseline: 1.0148x; 1.0148x over previous
//
#include <hip/hip_runtime.h>
#include <hip/hip_bf16.h>
#include <stdint.h>

typedef __hip_bfloat16 bf16;
typedef __attribute__((ext_vector_type(8))) short short8;
typedef __attribute__((ext_vector_type(4))) float f32x4;

__device__ __forceinline__ bf16 f2b(float v){ return __float2bfloat16(v); }
__device__ __forceinline__ short s2s(float v){ bf16 b = __float2bfloat16(v); return *reinterpret_cast<short*>(&b); }
__device__ __forceinline__ short8 s8zero()
{
    short8 z;
    for (int i = 0; i < 8; ++i) z[i] = 0;
    return z;
}

// ============ ONE fused weight-prep kernel (9 transforms, segment if-chain) ============
__global__ void prep_weights(const float* __restrict__ ew1, const float* __restrict__ ew2,
                             const float* __restrict__ ew3, const float* __restrict__ dw1,
                             const float* __restrict__ dw2, const float* __restrict__ dw3,
                             const float* __restrict__ kw,  const float* __restrict__ f1w,
                             const float* __restrict__ f2w,
                             bf16* __restrict__ wte1, bf16* __restrict__ wte2,
                             bf16* __restrict__ wte3, bf16* __restrict__ wtb4,
                             bf16* __restrict__ wtb5, bf16* __restrict__ wtb6,
                             bf16* __restrict__ kwt,  bf16* __restrict__ wtf1,
                             bf16* __restrict__ wtf2)
{
    int idx = blockIdx.x * blockDim.x + threadIdx.x;
    if (idx < 1536) {
        int q = idx >> 9, r = idx & 511;
        int co = r >> 5, k = r & 31;
        int j = k >> 3, ci = k & 7;
        int t = 4 * q + j;
        float v = (ci < 3 && t < 9) ? ew1[((size_t)co * 3 + ci) * 9 + t] : 0.f;
        wte1[idx] = f2b(v);
        return;
    }
    idx -= 1536;
    if (idx < 5120) {
        int p = idx >> 10, r = idx & 1023;
        int co = r >> 5, k = r & 31;
        int t = 2 * p + (k >> 4);
        int ch = k & 15;
        float v = (t <= 8) ? ew2[((size_t)co * 16 + ch) * 9 + t] : 0.f;
        wte2[idx] = f2b(v);
        return;
    }
    idx -= 5120;
    if (idx < 18432) {
        int co = idx / 288;
        int r  = idx - co * 288;
        int ci = r / 9, t = r - ci * 9;
        wte3[((size_t)t * 64 + co) * 32 + ci] = f2b(ew3[idx]);
        return;
    }
    idx -= 18432;
    if (idx < 36864) {
        int ci = idx / 576;
        int r  = idx - ci * 576;
        int co = r / 9, t = r - co * 9;
        wtb4[((size_t)t * 64 + co) * 64 + ci] = f2b(dw1[idx]);
        return;
    }
    idx -= 36864;
    if (idx < 18432) {
        int ci = idx / 288;
        int r  = idx - ci * 288;
        int co = r / 9, t = r - co * 9;
        wtb5[((size_t)t * 32 + co) * 64 + ci] = f2b(dw2[idx]);
        return;
    }
    idx -= 18432;
    if (idx < 4608) {
        int ci = idx / 144;
        int r  = idx - ci * 144;
        int co = r / 9, t = r - co * 9;
        wtb6[((size_t)t * 16 + co) * 32 + ci] = f2b(dw3[idx]);
        return;
    }
    idx -= 4608;
    if (idx < 458752) {
        int e = idx >> 12, kk = idx & 4095;
        int pos = kk >> 6, ci = kk & 63;
        float v = (e < 110) ? kw[(size_t)e * 4096 + ci * 64 + pos] : 0.f;
        kwt[idx] = f2b(v);
        return;
    }
    idx -= 458752;
    if (idx < 655360) {
        int n = idx / 1280, k = idx - n * 1280;
        float v = (k < 1210) ? f1w[(size_t)n * 1210 + k] : 0.f;
        wtf1[idx] = f2b(v);
        return;
    }
    idx -= 655360;
    if (idx < 131072) {
        wtf2[idx] = f2b(f2w[idx]);
        return;
    }
}

// ============ FUSED encoder (round-15 version, 256 threads) ============
__global__ __launch_bounds__(256)
void enc123_fused(const float* __restrict__ xg,
                  const bf16* __restrict__ wte1, const float* __restrict__ eb1,
                  const bf16* __restrict__ wte2, const float* __restrict__ eb2,
                  const bf16* __restrict__ wte3, const float* __restrict__ eb3,
                  bf16* __restrict__ h3g)
{
    __shared__ char smem[57728];
    short8* H1  = (short8*)smem;             // 2312 short8
    short8* Xs1 = (short8*)(smem + 36992);   // 1156 short8
    short8* H2  = (short8*)(smem + 36992);   // 1296 short8 — overlays Xs1

    const int img = blockIdx.x;
    const int tid = threadIdx.x;
    const float* xi = xg + (size_t)img * 3072;

    for (int e = tid; e < 1156; e += 256) {
        int hr = e / 34, wc = e % 34;
        int hi = hr - 1, wi = wc - 1;
        short8 v = s8zero();
        if ((unsigned)hi < 32u && (unsigned)wi < 32u) {
            int p = hi * 32 + wi;
            v[0] = s2s(xi[p]);
            v[1] = s2s(xi[p + 1024]);
            v[2] = s2s(xi[p + 2048]);
        }
        Xs1[e] = v;
    }
    for (int e = tid; e < 264; e += 256) {
        int c8 = e & 1, q = e >> 1;
        int pl = q / 33, j = q % 33;
        int pos = (j < 17) ? j : (j - 16) * 17;
        H1[(pl * 289 + pos) * 2 + c8] = s8zero();
    }
    __syncthreads();

    const int wv = tid >> 6, lane = tid & 63;
    const int lp = lane & 15, lq = lane >> 4;

    {
        short8 wf[3];
        #pragma unroll
        for (int q = 0; q < 3; ++q)
            wf[q] = *reinterpret_cast<const short8*>(wte1 + (size_t)(q * 16 + lp) * 32 + lq * 8);
        float bv[4];
        #pragma unroll
        for (int r = 0; r < 4; ++r) bv[r] = eb1[lq * 4 + r];

        for (int mt = wv * 16; mt < wv * 16 + 16; ++mt) {
            int m = mt * 16 + lp;
            int ho = m >> 5, wo = m & 31;
            f32x4 acc = {0.f, 0.f, 0.f, 0.f};
            #pragma unroll
            for (int q = 0; q < 3; ++q) {
                int t = 4 * q + lq;
                if (t > 8) t = 8;
                int pos = (ho + t / 3) * 34 + (wo + t % 3);
                acc = __builtin_amdgcn_mfma_f32_16x16x32_bf16(wf[q], Xs1[pos], acc, 0, 0, 0);
            }
            int pl  = (ho & 1) * 2 + (wo & 1);
            int pos = ((ho >> 1) + 1) * 17 + ((wo >> 1) + 1);
            int slot = (pl * 289 + pos) * 2 + ((lq >> 1) ^ (pos & 1));
            __align__(8) bf16 ov[4];
            #pragma unroll
            for (int r = 0; r < 4; ++r) ov[r] = f2b(fmaxf(acc[r] + bv[r], 0.f));
            *reinterpret_cast<uint2*>(reinterpret_cast<char*>(&H1[slot]) + (lq & 1) * 8)
                = *reinterpret_cast<uint2*>(ov);
        }
    }
    __syncthreads();

    for (int e = tid; e < 272; e += 256) {
        int c8 = e & 3, q = e >> 2;
        int pl = q / 17, j = q % 17;
        int pos = (j < 9) ? j : (j - 8) * 9;
        H2[(pl * 81 + pos) * 4 + c8] = s8zero();
    }
    {
        const int nt = wv & 1, mh = wv >> 1;
        short8 wf[5];
        #pragma unroll
        for (int p = 0; p < 5; ++p)
            wf[p] = *reinterpret_cast<const short8*>(wte2 + ((size_t)(p * 32 + nt * 16 + lp)) * 32 + lq * 8);
        float bv[4];
        #pragma unroll
        for (int r = 0; r < 4; ++r) bv[r] = eb2[nt * 16 + lq * 4 + r];

        for (int mt = mh * 8; mt < mh * 8 + 8; ++mt) {
            int m = mt * 16 + lp;
            int ho = m >> 4, wo = m & 15;
            f32x4 acc = {0.f, 0.f, 0.f, 0.f};
            #pragma unroll
            for (int p = 0; p < 5; ++p) {
                const int tA = 2 * p, tB = (p < 4) ? 2 * p + 1 : 8;
                const int khA = tA / 3, kwA = tA % 3;
                const int paA = (khA == 1) ? 0 : 1, dhA = (khA == 0) ? -1 : 0;
                const int pbA = (kwA == 1) ? 0 : 1, dwA = (kwA == 0) ? -1 : 0;
                const int khB = tB / 3, kwB = tB % 3;
                const int paB = (khB == 1) ? 0 : 1, dhB = (khB == 0) ? -1 : 0;
                const int pbB = (kwB == 1) ? 0 : 1, dwB = (kwB == 0) ? -1 : 0;
                int posA = (ho + dhA + 1) * 17 + (wo + dwA + 1);
                int posB = (ho + dhB + 1) * 17 + (wo + dwB + 1);
                int idxA = ((paA * 2 + pbA) * 289 + posA) * 2 + ((lq & 1) ^ (posA & 1));
                int idxB = ((paB * 2 + pbB) * 289 + posB) * 2 + ((lq & 1) ^ (posB & 1));
                short8 b = H1[(lq < 2) ? idxA : idxB];
                acc = __builtin_amdgcn_mfma_f32_16x16x32_bf16(wf[p], b, acc, 0, 0, 0);
            }
            int pl  = (ho & 1) * 2 + (wo & 1);
            int pos = ((ho >> 1) + 1) * 9 + ((wo >> 1) + 1);
            int c8w = nt * 2 + (lq >> 1);
            int slot = (pl * 81 + pos) * 4 + (c8w ^ (pos & 3));
            __align__(8) bf16 ov[4];
            #pragma unroll
            for (int r = 0; r < 4; ++r) ov[r] = f2b(fmaxf(acc[r] + bv[r], 0.f));
            *reinterpret_cast<uint2*>(reinterpret_cast<char*>(&H2[slot]) + (lq & 1) * 8)
                = *reinterpret_cast<uint2*>(ov);
        }
    }
    __syncthreads();

    {
        const int nt = wv;
        short8 wf[9];
        #pragma unroll
        for (int t = 0; t < 9; ++t)
            wf[t] = *reinterpret_cast<const short8*>(wte3 + ((size_t)(t * 64 + nt * 16 + lp)) * 32 + lq * 8);
        float bv[4];
        #pragma unroll
        for (int r = 0; r < 4; ++r) bv[r] = eb3[nt * 16 + lq * 4 + r];

        bf16* yi = h3g + (size_t)img * 4096;
        for (int mt = 0; mt < 4; ++mt) {
            int m = mt * 16 + lp;
            int ho = m >> 3, wo = m & 7;
            f32x4 acc = {0.f, 0.f, 0.f, 0.f};
            #pragma unroll
            for (int t = 0; t < 9; ++t) {
                const int kh = t / 3, kw2 = t % 3;
                const int pa = (kh == 1) ? 0 : 1, dh = (kh == 0) ? -1 : 0;
                const int pb = (kw2 == 1) ? 0 : 1, dw = (kw2 == 0) ? -1 : 0;
                int pos = (ho + dh + 1) * 9 + (wo + dw + 1);
                int idx = ((pa * 2 + pb) * 81 + pos) * 4 + (lq ^ (pos & 3));
                acc = __builtin_amdgcn_mfma_f32_16x16x32_bf16(wf[t], H2[idx], acc, 0, 0, 0);
            }
            __align__(8) bf16 ov[4];
            #pragma unroll
            for (int r = 0; r < 4; ++r) ov[r] = f2b(fmaxf(acc[r] + bv[r], 0.f));
            *reinterpret_cast<uint2*>(yi + ((size_t)(ho * 8 + wo)) * 64 + nt * 16 + lq * 4)
                = *reinterpret_cast<uint2*>(ov);
        }
    }
}

// ============ HALF-IMAGE dec1+dec2: 2 blocks/img, 26.5 KB LDS -> 6 blocks/CU ============
// Block (img, half): computes d2p quarter-rows hq in [half*8, half*8+8).
// Recomputes dec1 rows [half*8, half*8+8] (one halo quarter-row duplicated).
__global__ __launch_bounds__(256)
void dec12_half(const bf16* __restrict__ h3g,
                const bf16* __restrict__ wtb4, const float* __restrict__ db1,
                const bf16* __restrict__ wtb5, const float* __restrict__ db2,
                bf16* __restrict__ d2p)
{
    __shared__ short8 H3s[6 * 9 * 8];      //  6,912 B  (local h3 rows r3base..r3base+5)
    __shared__ short8 D1s[9 * 17 * 8];     // 19,584 B  (local d1 rows h0..h0+8, col 16 halo)

    const int img  = blockIdx.x >> 1;
    const int half = blockIdx.x & 1;
    const int h0   = half * 8;             // global d1/quarter-row base
    const int r3b  = half * 4;             // global h3 row base
    const int tid  = threadIdx.x;
    const bf16* xi = h3g + (size_t)img * 4096;

    // phase 0: stage h3 slice (zero-padded), zero-init all of D1s
    for (int e = tid; e < 432; e += 256) {
        int c8 = e & 7, pos = e >> 3;
        int lr = pos / 9, wc = pos % 9;
        int gr = r3b + lr;
        short8 v = s8zero();
        if (gr < 8 && wc < 8)
            v = *reinterpret_cast<const short8*>(xi + ((size_t)(gr * 8 + wc)) * 64 + c8 * 8);
        H3s[pos * 8 + (c8 ^ (pos & 7))] = v;
    }
    for (int e = tid; e < 1224; e += 256) D1s[e] = s8zero();
    __syncthreads();

    const int wv = tid >> 6, lane = tid & 63;
    const int lp = lane & 15, lq = lane >> 4;

    // ---- dec1: h3 rows [r3b, r3b+NQ) -> D1s local rows 0..8 ----
    {
        const int nt = wv;                  // 4 waves x 4 n-tiles (64 cout)
        const int NQ = (half == 0) ? 5 : 4; // quarter-rows of h3 to process
        const int NPOS = NQ * 8;
        short8 wf[9][2];
        #pragma unroll
        for (int t = 0; t < 9; ++t) {
            const bf16* wp = wtb4 + ((size_t)t * 64 + nt * 16 + lp) * 64 + lq * 8;
            wf[t][0] = *reinterpret_cast<const short8*>(wp);
            wf[t][1] = *reinterpret_cast<const short8*>(wp + 32);
        }
        float bv[4];
        #pragma unroll
        for (int r = 0; r < 4; ++r) bv[r] = db1[nt * 16 + lq * 4 + r];

        const int c8w = nt * 2 + (lq >> 1);
        const int NPT = (NPOS + 15) / 16;
        for (int pt = 0; pt < NPT; ++pt) {
            int m = pt * 16 + lp;
            bool mvalid = m < NPOS;
            int mm = mvalid ? m : 0;
            int lr3 = mm >> 3, wq3 = mm & 7;
            f32x4 zero = {0.f, 0.f, 0.f, 0.f};
            f32x4 acc[4] = {zero, zero, zero, zero};
            #pragma unroll
            for (int kh = 0; kh < 3; ++kh) {
                #pragma unroll
                for (int kw = 0; kw < 3; ++kw) {
                    const int pa = (kh + 1) & 1, pb = (kw + 1) & 1;
                    const int oh = (pa + 1 - kh) >> 1, ow = (pb + 1 - kw) >> 1;
                    const int cls = pa * 2 + pb;
                    const int t = kh * 3 + kw;
                    int pos = (lr3 + oh) * 9 + (wq3 + ow);
                    int sw = pos & 7;
                    acc[cls] = __builtin_amdgcn_mfma_f32_16x16x32_bf16(wf[t][0], H3s[pos * 8 + (lq ^ sw)], acc[cls], 0, 0, 0);
                    acc[cls] = __builtin_amdgcn_mfma_f32_16x16x32_bf16(wf[t][1], H3s[pos * 8 + ((4 + lq) ^ sw)], acc[cls], 0, 0, 0);
                }
            }
            #pragma unroll
            for (int cls = 0; cls < 4; ++cls) {
                int pa = cls >> 1, pb = cls & 1;
                int ld = lr3 * 2 + pa;          // local d1 row
                int wo = wq3 * 2 + pb;
                if (mvalid && ld <= 8) {
                    int pos = ld * 17 + wo;
                    int slot = pos * 8 + (c8w ^ (pos & 7));
                    __align__(8) bf16 ov[4];
                    #pragma unroll
                    for (int r = 0; r < 4; ++r) ov[r] = f2b(fmaxf(acc[cls][r] + bv[r], 0.f));
                    *reinterpret_cast<uint2*>(reinterpret_cast<char*>(&D1s[slot]) + (lq & 1) * 8)
                        = *reinterpret_cast<uint2*>(ov);
                }
            }
        }
    }
    __syncthreads();

    // ---- dec2: local rows 0..7 -> d2p global quarter-rows h0..h0+7 ----
    {
        const int nt = wv & 1;
        const int mt0 = (wv >> 1) * 4;      // 2 row-groups x 4 rows
        short8 wf[9][2];
        #pragma unroll
        for (int t = 0; t < 9; ++t) {
            const bf16* wp = wtb5 + ((size_t)t * 32 + nt * 16 + lp) * 64 + lq * 8;
            wf[t][0] = *reinterpret_cast<const short8*>(wp);
            wf[t][1] = *reinterpret_cast<const short8*>(wp + 32);
        }
        float bv[4];
        #pragma unroll
        for (int r = 0; r < 4; ++r) bv[r] = db2[nt * 16 + lq * 4 + r];

        bf16* yo = d2p + (size_t)img * 32768;
        for (int mt = mt0; mt < mt0 + 4; ++mt) {
            const int hql = mt, wq = lp;    // local quarter row / col
            f32x4 zero = {0.f, 0.f, 0.f, 0.f};
            f32x4 acc[4] = {zero, zero, zero, zero};
            #pragma unroll
            for (int kh = 0; kh < 3; ++kh) {
                #pragma unroll
                for (int kw = 0; kw < 3; ++kw) {
                    const int pa = (kh + 1) & 1, pb = (kw + 1) & 1;
                    const int oh = (pa + 1 - kh) >> 1, ow = (pb + 1 - kw) >> 1;
                    const int cls = pa * 2 + pb;
                    const int t = kh * 3 + kw;
                    int pos = (hql + oh) * 17 + (wq + ow);
                    int sw = pos & 7;
                    acc[cls] = __builtin_amdgcn_mfma_f32_16x16x32_bf16(wf[t][0], D1s[pos * 8 + (lq ^ sw)], acc[cls], 0, 0, 0);
                    acc[cls] = __builtin_amdgcn_mfma_f32_16x16x32_bf16(wf[t][1], D1s[pos * 8 + ((4 + lq) ^ sw)], acc[cls], 0, 0, 0);
                }
            }
            const int hqg = h0 + hql;
            #pragma unroll
            for (int cls = 0; cls < 4; ++cls) {
                __align__(8) bf16 ov[4];
                #pragma unroll
                for (int r = 0; r < 4; ++r) ov[r] = f2b(fmaxf(acc[cls][r] + bv[r], 0.f));
                size_t off = (size_t)cls * 8192 + (size_t)nt * 4096 + (hqg * 16 + wq) * 16 + lq * 4;
                *reinterpret_cast<uint2*>(yo + off) = *reinterpret_cast<uint2*>(ov);
            }
        }
    }
}

// ============ emb = sigmoid(h3b @ kwt^T + kb); n-tile via blockIdx.y ============
__global__ __launch_bounds__(256)
void emb_mfma(const bf16* __restrict__ h3b, const bf16* __restrict__ kwt,
              const float* __restrict__ kb, float* __restrict__ emb)
{
    __shared__ f32x4 Ls[3][64];
    const int imgbase = blockIdx.x * 16;
    const int nt = blockIdx.y;
    const int w = threadIdx.x >> 6, lane = threadIdx.x & 63;
    const int lp = lane & 15, lq = lane >> 4;
    const int k0 = w * 1024;

    f32x4 acc = {0.f, 0.f, 0.f, 0.f};
    const bf16* bp = h3b + (size_t)(imgbase + lp) * 4096 + k0 + lq * 8;
    const bf16* ap = kwt + (size_t)(nt * 16 + lp) * 4096 + k0 + lq * 8;
    for (int ks = 0; ks < 32; ++ks) {
        short8 bfrag = *reinterpret_cast<const short8*>(bp + ks * 32);
        short8 afrag = *reinterpret_cast<const short8*>(ap + ks * 32);
        acc = __builtin_amdgcn_mfma_f32_16x16x32_bf16(afrag, bfrag, acc, 0, 0, 0);
    }
    if (w > 0) Ls[w - 1][lane] = acc;
    __syncthreads();
    if (w == 0) {
        #pragma unroll
        for (int ww = 0; ww < 3; ++ww) acc += Ls[ww][lane];
        const int e0 = nt * 16 + lq * 4;
        #pragma unroll
        for (int r = 0; r < 4; ++r) {
            int e = e0 + r;
            if (e < 110) {
                float v = acc[r] + kb[e];
                emb[(size_t)(imgbase + lp) * 110 + e] = 1.f / (1.f + expf(-v));
            }
        }
    }
}

// ============ dec3: d2p (parity layout) -> conv_t1 -> fused 1x1 -> dec fp32 NCHW ============
__global__ __launch_bounds__(256)
void convt1_mfma_fused(const bf16* __restrict__ d2p, const bf16* __restrict__ wtb,
                       const float* __restrict__ bias,
                       const float* __restrict__ w4, const float* __restrict__ b4,
                       float* __restrict__ dec)
{
    constexpr int C8 = 4;
    constexpr int HR = 18, WR = 34, NPOS = HR * WR;
    __shared__ short8 Xs[NPOS * C8];

    const int img  = blockIdx.x >> 1;
    const int half = blockIdx.x & 1;
    const int hbase = half * 16;
    const bf16* xi = d2p + (size_t)img * 32768;

    for (int e = threadIdx.x; e < NPOS * C8; e += 256) {
        int c8 = e & 3, pos = e >> 2;
        int hr = pos / WR, wr = pos % WR;
        int hi = hbase - 1 + hr, wi = wr - 1;
        short8 v = s8zero();
        if ((unsigned)hi < 32u && (unsigned)wi < 32u) {
            int cls = ((hi & 1) << 1) | (wi & 1);
            size_t src = (size_t)cls * 8192 + (size_t)(c8 >> 1) * 4096
                       + (((hi >> 1) << 4) + (wi >> 1)) * 16 + (c8 & 1) * 8;
            v = *reinterpret_cast<const short8*>(xi + src);
        }
        Xs[pos * C8 + (c8 ^ (pos & 3))] = v;
    }
    __syncthreads();

    const int wv = threadIdx.x >> 6, lane = threadIdx.x & 63;
    const int lp = lane & 15, lq = lane >> 4;

    short8 wf[9];
    #pragma unroll
    for (int t = 0; t < 9; ++t)
        wf[t] = *reinterpret_cast<const short8*>(wtb + ((size_t)t * 16 + lp) * 32 + lq * 8);
    float bv[4];
    #pragma unroll
    for (int r = 0; r < 4; ++r) bv[r] = bias[lq * 4 + r];
    float w4r[3][4];
    #pragma unroll
    for (int j = 0; j < 3; ++j)
        #pragma unroll
        for (int r = 0; r < 4; ++r) w4r[j][r] = w4[j * 16 + lq * 4 + r];
    float b4r[3] = {b4[0], b4[1], b4[2]};

    for (int mt = wv; mt < 32; mt += 4) {
        int m = mt * 16 + lp;
        int hol = m >> 5, wo = m & 31;
        f32x4 acc = {0.f, 0.f, 0.f, 0.f};
        #pragma unroll
        for (int t = 0; t < 9; ++t) {
            int kh = t / 3, kw = t % 3;
            int pos = (hol + 2 - kh) * WR + (wo + 2 - kw);
            short8 b0 = Xs[pos * C8 + (lq ^ (pos & 3))];
            acc = __builtin_amdgcn_mfma_f32_16x16x32_bf16(wf[t], b0, acc, 0, 0, 0);
        }
        float s0 = 0.f, s1 = 0.f, s2 = 0.f;
        #pragma unroll
        for (int r = 0; r < 4; ++r) {
            float v = fmaxf(acc[r] + bv[r], 0.f);
            s0 += v * w4r[0][r]; s1 += v * w4r[1][r]; s2 += v * w4r[2][r];
        }
        s0 += __shfl_xor(s0, 16); s0 += __shfl_xor(s0, 32);
        s1 += __shfl_xor(s1, 16); s1 += __shfl_xor(s1, 32);
        s2 += __shfl_xor(s2, 16); s2 += __shfl_xor(s2, 32);
        if (lq == 0) {
            int ho = hbase + hol;
            size_t base = (size_t)img * 3072 + ho * 32 + wo;
            dec[base]        = s0 + b4r[0];
            dec[base + 1024] = s1 + b4r[1];
            dec[base + 2048] = s2 + b4r[2];
        }
    }
}

// ============ KDE: 64 blocks -> fdb bf16 [64][1280] (padded) ============
__global__ __launch_bounds__(256)
void kde_kernel(const float* __restrict__ emb, bf16* __restrict__ fdb)
{
    __shared__ float es[3520];
    const int b = blockIdx.x, tid = threadIdx.x;
    for (int i = tid; i < 3520; i += 256) es[i] = emb[(size_t)b * 3520 + i];
    __syncthreads();
    if (tid < 110) {
        float dens[11];
        #pragma unroll
        for (int j = 0; j < 11; ++j) dens[j] = 0.f;
        for (int n = 0; n < 32; ++n) {
            float e = es[n * 110 + tid];
            #pragma unroll
            for (int j = 0; j < 11; ++j) {
                float d = 0.1f * j - e;
                dens[j] += __expf(-50.f * d * d);
            }
        }
        float s = 0.f;
        #pragma unroll
        for (int j = 0; j < 11; ++j) s += dens[j];
        float inv = 1.f / s;
        #pragma unroll
        for (int j = 0; j < 11; ++j)
            fdb[(size_t)b * 1280 + tid * 11 + j] = f2b(dens[j] * inv);
    } else if (tid >= 128 && tid < 198) {
        fdb[(size_t)b * 1280 + 1210 + (tid - 128)] = f2b(0.f);
    }
}

// ============ dense MFMA layer ============
template<int K, int N, int RELU>
__global__ __launch_bounds__(256)
void dense_mfma(const bf16* __restrict__ inb, const bf16* __restrict__ wtb,
                const float* __restrict__ bias, bf16* __restrict__ outb)
{
    __shared__ f32x4 Ls[3][64];
    constexpr int KW = K / 4;
    const int mt = blockIdx.x, nt = blockIdx.y;
    const int w = threadIdx.x >> 6, lane = threadIdx.x & 63;
    const int lp = lane & 15, lq = lane >> 4;
    const int k0 = w * KW;

    f32x4 acc = {0.f, 0.f, 0.f, 0.f};
    const bf16* bp = inb + (size_t)(mt * 16 + lp) * K + k0 + lq * 8;
    const bf16* ap = wtb + (size_t)(nt * 16 + lp) * K + k0 + lq * 8;
    for (int ks = 0; ks < KW / 32; ++ks) {
        short8 bfrag = *reinterpret_cast<const short8*>(bp + ks * 32);
        short8 afrag = *reinterpret_cast<const short8*>(ap + ks * 32);
        acc = __builtin_amdgcn_mfma_f32_16x16x32_bf16(afrag, bfrag, acc, 0, 0, 0);
    }
    if (w > 0) Ls[w - 1][lane] = acc;
    __syncthreads();
    if (w == 0) {
        #pragma unroll
        for (int ww = 0; ww < 3; ++ww) acc += Ls[ww][lane];
        const int b = mt * 16 + lp;
        const int o0 = nt * 16 + lq * 4;
        __align__(8) bf16 ov[4];
        #pragma unroll
        for (int r = 0; r < 4; ++r) {
            float v = acc[r] + bias[o0 + r];
            if (RELU) v = fmaxf(v, 0.f);
            ov[r] = f2b(v);
        }
        *reinterpret_cast<uint2*>(outb + (size_t)b * N + o0) = *reinterpret_cast<uint2*>(ov);
    }
}

// ============ f3: 256 -> 4, one block ============
__global__ __launch_bounds__(256)
void f3_kernel(const bf16* __restrict__ m2b, const float* __restrict__ f3w,
               const float* __restrict__ f3b, float* __restrict__ logits)
{
    __shared__ float m2s[64 * 256];
    const int tid = threadIdx.x;
    for (int i = tid; i < 16384; i += 256) m2s[i] = __bfloat162float(m2b[i]);
    __syncthreads();
    int b = tid >> 2, o = tid & 3;
    float a = f3b[o];
    const float* wr = f3w + o * 256;
    for (int k = 0; k < 256; ++k) a += m2s[b * 256 + k] * wr[k];
    logits[b * 4 + o] = a;
}

extern "C" void kernel_launch(void* const* d_in, const int* in_sizes, int n_in,
                              void* d_out, int out_size, void* d_ws, size_t ws_size,
                              hipStream_t stream)
{
    const float* x    = (const float*)d_in[0];
    const float* ew1  = (const float*)d_in[1];
    const float* eb1  = (const float*)d_in[2];
    const float* ew2  = (const float*)d_in[3];
    const float* eb2  = (const float*)d_in[4];
    const float* ew3  = (const float*)d_in[5];
    const float* eb3  = (const float*)d_in[6];
    const float* kw   = (const float*)d_in[7];
    const float* kb   = (const float*)d_in[8];
    const float* dw1  = (const float*)d_in[9];
    const float* db1  = (const float*)d_in[10];
    const float* dw2  = (const float*)d_in[11];
    const float* db2  = (const float*)d_in[12];
    const float* dw3  = (const float*)d_in[13];
    const float* db3  = (const float*)d_in[14];
    const float* dw4  = (const float*)d_in[15];
    const float* db4  = (const float*)d_in[16];
    const float* f1w  = (const float*)d_in[17];
    const float* f1b  = (const float*)d_in[18];
    const float* f2w  = (const float*)d_in[19];
    const float* f2b_ = (const float*)d_in[20];
    const float* f3w  = (const float*)d_in[21];
    const float* f3b  = (const float*)d_in[22];

    // ---------- workspace ----------
    char* ws = (char*)d_ws;
    float* emb  = (float*)(ws + 0);          //   901,120
    bf16*  fdb  = (bf16*) (ws + 901120);     //   163,840
    bf16*  m1b  = (bf16*) (ws + 1064960);    //    65,536
    bf16*  m2b  = (bf16*) (ws + 1130496);    //    32,768
    bf16*  wte1 = (bf16*) (ws + 1163264);    //     3,072
    bf16*  wte2 = (bf16*) (ws + 1166336);    //    10,240
    bf16*  wte3 = (bf16*) (ws + 1176576);    //    36,864
    bf16*  wtb4 = (bf16*) (ws + 1213440);    //    73,728
    bf16*  wtb5 = (bf16*) (ws + 1287168);    //    36,864
    bf16*  wtb6 = (bf16*) (ws + 1324032);    //     9,216
    bf16*  kwt  = (bf16*) (ws + 1333248);    //   917,504
    bf16*  wtf1 = (bf16*) (ws + 2250752);    // 1,310,720
    bf16*  wtf2 = (bf16*) (ws + 3561472);    //   262,144
    const size_t FIXED = 3823616;

    // per image: h3b 8 KB + d2p 64 KB
    const size_t PER_IMG = 73728;
    int CHUNK = 2048;
    while (CHUNK > 16 && FIXED + (size_t)CHUNK * PER_IMG > ws_size) CHUNK >>= 1;
    const int NCHUNK = 2048 / CHUNK;

    char* p   = ws + FIXED;
    bf16* h3b = (bf16*)(p);
    bf16* d2p = (bf16*)(p + (size_t)CHUNK * 8192);

    float* logits = (float*)d_out;            // 64*4
    float* dec    = (float*)d_out + 256;      // 2048*3*32*32 NCHW

    // ---- fused weight prep (1 launch) ----
    prep_weights<<<(1330176 + 255)/256, 256, 0, stream>>>(
        ew1, ew2, ew3, dw1, dw2, dw3, kw, f1w, f2w,
        wte1, wte2, wte3, wtb4, wtb5, wtb6, kwt, wtf1, wtf2);

    for (int c = 0; c < NCHUNK; ++c) {
        const float* xc   = x   + (size_t)c * CHUNK * 3 * 1024;
        float*       decc = dec + (size_t)c * CHUNK * 3 * 1024;
        float*       embc = emb + (size_t)c * CHUNK * 110;

        enc123_fused<<<CHUNK, 256, 0, stream>>>(xc, wte1, eb1, wte2, eb2, wte3, eb3, h3b);
        emb_mfma<<<dim3(CHUNK/16, 7), 256, 0, stream>>>(h3b, kwt, kb, embc);
        dec12_half<<<CHUNK*2, 256, 0, stream>>>(h3b, wtb4, db1, wtb5, db2, d2p);
        convt1_mfma_fused<<<CHUNK*2, 256, 0, stream>>>(d2p, wtb6, db3, dw4, db4, decc);
    }

    // classifier: KDE -> f1 (MFMA) -> f2 (MFMA) -> f3
    kde_kernel<<<64, 256, 0, stream>>>(emb, fdb);
    dense_mfma<1280, 512, 1><<<dim3(4, 32), 256, 0, stream>>>(fdb, wtf1, f1b, m1b);
    dense_mfma<512, 256, 1> <<<dim3(4, 16), 256, 0, stream>>>(m1b, wtf2, f2b_, m2b);
    f3_kernel<<<1, 256, 0, stream>>>(m2b, f3w, f3b, logits);
}

// Round 20
// 213.737 us; speedup vs baseline: 1.1344x; 1.1178x over previous
//
#include <hip/hip_runtime.h>
#include <hip/hip_bf16.h>
#include <stdint.h>

typedef __hip_bfloat16 bf16;
typedef __attribute__((ext_vector_type(8))) short short8;
typedef __attribute__((ext_vector_type(4))) float f32x4;

__device__ __forceinline__ bf16 f2b(float v){ return __float2bfloat16(v); }
__device__ __forceinline__ short s2s(float v){ bf16 b = __float2bfloat16(v); return *reinterpret_cast<short*>(&b); }
__device__ __forceinline__ short8 s8zero()
{
    short8 z;
    for (int i = 0; i < 8; ++i) z[i] = 0;
    return z;
}

// ============ ONE fused weight-prep kernel (9 transforms, segment if-chain) ============
__global__ void prep_weights(const float* __restrict__ ew1, const float* __restrict__ ew2,
                             const float* __restrict__ ew3, const float* __restrict__ dw1,
                             const float* __restrict__ dw2, const float* __restrict__ dw3,
                             const float* __restrict__ kw,  const float* __restrict__ f1w,
                             const float* __restrict__ f2w,
                             bf16* __restrict__ wte1, bf16* __restrict__ wte2,
                             bf16* __restrict__ wte3, bf16* __restrict__ wtb4,
                             bf16* __restrict__ wtb5, bf16* __restrict__ wtb6,
                             bf16* __restrict__ kwt,  bf16* __restrict__ wtf1,
                             bf16* __restrict__ wtf2)
{
    int idx = blockIdx.x * blockDim.x + threadIdx.x;
    if (idx < 1536) {
        int q = idx >> 9, r = idx & 511;
        int co = r >> 5, k = r & 31;
        int j = k >> 3, ci = k & 7;
        int t = 4 * q + j;
        float v = (ci < 3 && t < 9) ? ew1[((size_t)co * 3 + ci) * 9 + t] : 0.f;
        wte1[idx] = f2b(v);
        return;
    }
    idx -= 1536;
    if (idx < 5120) {
        int p = idx >> 10, r = idx & 1023;
        int co = r >> 5, k = r & 31;
        int t = 2 * p + (k >> 4);
        int ch = k & 15;
        float v = (t <= 8) ? ew2[((size_t)co * 16 + ch) * 9 + t] : 0.f;
        wte2[idx] = f2b(v);
        return;
    }
    idx -= 5120;
    if (idx < 18432) {
        int co = idx / 288;
        int r  = idx - co * 288;
        int ci = r / 9, t = r - ci * 9;
        wte3[((size_t)t * 64 + co) * 32 + ci] = f2b(ew3[idx]);
        return;
    }
    idx -= 18432;
    if (idx < 36864) {
        int ci = idx / 576;
        int r  = idx - ci * 576;
        int co = r / 9, t = r - co * 9;
        wtb4[((size_t)t * 64 + co) * 64 + ci] = f2b(dw1[idx]);
        return;
    }
    idx -= 36864;
    if (idx < 18432) {
        int ci = idx / 288;
        int r  = idx - ci * 288;
        int co = r / 9, t = r - co * 9;
        wtb5[((size_t)t * 32 + co) * 64 + ci] = f2b(dw2[idx]);
        return;
    }
    idx -= 18432;
    if (idx < 4608) {
        int ci = idx / 144;
        int r  = idx - ci * 144;
        int co = r / 9, t = r - co * 9;
        wtb6[((size_t)t * 16 + co) * 32 + ci] = f2b(dw3[idx]);
        return;
    }
    idx -= 4608;
    if (idx < 458752) {
        int e = idx >> 12, kk = idx & 4095;
        int pos = kk >> 6, ci = kk & 63;
        float v = (e < 110) ? kw[(size_t)e * 4096 + ci * 64 + pos] : 0.f;
        kwt[idx] = f2b(v);
        return;
    }
    idx -= 458752;
    if (idx < 655360) {
        int n = idx / 1280, k = idx - n * 1280;
        float v = (k < 1210) ? f1w[(size_t)n * 1210 + k] : 0.f;
        wtf1[idx] = f2b(v);
        return;
    }
    idx -= 655360;
    if (idx < 131072) {
        wtf2[idx] = f2b(f2w[idx]);
        return;
    }
}

// ============ FUSED encoder: x fp32 -> (LDS h1 -> LDS h2) -> h3b bf16 NHWC ============
__global__ __launch_bounds__(256)
void enc123_fused(const float* __restrict__ xg,
                  const bf16* __restrict__ wte1, const float* __restrict__ eb1,
                  const bf16* __restrict__ wte2, const float* __restrict__ eb2,
                  const bf16* __restrict__ wte3, const float* __restrict__ eb3,
                  bf16* __restrict__ h3g)
{
    __shared__ char smem[57728];
    short8* H1  = (short8*)smem;             // 2312 short8
    short8* Xs1 = (short8*)(smem + 36992);   // 1156 short8
    short8* H2  = (short8*)(smem + 36992);   // 1296 short8 — overlays Xs1

    const int img = blockIdx.x;
    const int tid = threadIdx.x;
    const float* xi = xg + (size_t)img * 3072;

    for (int e = tid; e < 1156; e += 256) {
        int hr = e / 34, wc = e % 34;
        int hi = hr - 1, wi = wc - 1;
        short8 v = s8zero();
        if ((unsigned)hi < 32u && (unsigned)wi < 32u) {
            int p = hi * 32 + wi;
            v[0] = s2s(xi[p]);
            v[1] = s2s(xi[p + 1024]);
            v[2] = s2s(xi[p + 2048]);
        }
        Xs1[e] = v;
    }
    for (int e = tid; e < 264; e += 256) {
        int c8 = e & 1, q = e >> 1;
        int pl = q / 33, j = q % 33;
        int pos = (j < 17) ? j : (j - 16) * 17;
        H1[(pl * 289 + pos) * 2 + c8] = s8zero();
    }
    __syncthreads();

    const int wv = tid >> 6, lane = tid & 63;
    const int lp = lane & 15, lq = lane >> 4;

    {
        short8 wf[3];
        #pragma unroll
        for (int q = 0; q < 3; ++q)
            wf[q] = *reinterpret_cast<const short8*>(wte1 + (size_t)(q * 16 + lp) * 32 + lq * 8);
        float bv[4];
        #pragma unroll
        for (int r = 0; r < 4; ++r) bv[r] = eb1[lq * 4 + r];

        for (int mt = wv * 16; mt < wv * 16 + 16; ++mt) {
            int m = mt * 16 + lp;
            int ho = m >> 5, wo = m & 31;
            f32x4 acc = {0.f, 0.f, 0.f, 0.f};
            #pragma unroll
            for (int q = 0; q < 3; ++q) {
                int t = 4 * q + lq;
                if (t > 8) t = 8;
                int pos = (ho + t / 3) * 34 + (wo + t % 3);
                acc = __builtin_amdgcn_mfma_f32_16x16x32_bf16(wf[q], Xs1[pos], acc, 0, 0, 0);
            }
            int pl  = (ho & 1) * 2 + (wo & 1);
            int pos = ((ho >> 1) + 1) * 17 + ((wo >> 1) + 1);
            int slot = (pl * 289 + pos) * 2 + ((lq >> 1) ^ (pos & 1));
            __align__(8) bf16 ov[4];
            #pragma unroll
            for (int r = 0; r < 4; ++r) ov[r] = f2b(fmaxf(acc[r] + bv[r], 0.f));
            *reinterpret_cast<uint2*>(reinterpret_cast<char*>(&H1[slot]) + (lq & 1) * 8)
                = *reinterpret_cast<uint2*>(ov);
        }
    }
    __syncthreads();

    for (int e = tid; e < 272; e += 256) {
        int c8 = e & 3, q = e >> 2;
        int pl = q / 17, j = q % 17;
        int pos = (j < 9) ? j : (j - 8) * 9;
        H2[(pl * 81 + pos) * 4 + c8] = s8zero();
    }
    {
        const int nt = wv & 1, mh = wv >> 1;
        short8 wf[5];
        #pragma unroll
        for (int p = 0; p < 5; ++p)
            wf[p] = *reinterpret_cast<const short8*>(wte2 + ((size_t)(p * 32 + nt * 16 + lp)) * 32 + lq * 8);
        float bv[4];
        #pragma unroll
        for (int r = 0; r < 4; ++r) bv[r] = eb2[nt * 16 + lq * 4 + r];

        for (int mt = mh * 8; mt < mh * 8 + 8; ++mt) {
            int m = mt * 16 + lp;
            int ho = m >> 4, wo = m & 15;
            f32x4 acc = {0.f, 0.f, 0.f, 0.f};
            #pragma unroll
            for (int p = 0; p < 5; ++p) {
                const int tA = 2 * p, tB = (p < 4) ? 2 * p + 1 : 8;
                const int khA = tA / 3, kwA = tA % 3;
                const int paA = (khA == 1) ? 0 : 1, dhA = (khA == 0) ? -1 : 0;
                const int pbA = (kwA == 1) ? 0 : 1, dwA = (kwA == 0) ? -1 : 0;
                const int khB = tB / 3, kwB = tB % 3;
                const int paB = (khB == 1) ? 0 : 1, dhB = (khB == 0) ? -1 : 0;
                const int pbB = (kwB == 1) ? 0 : 1, dwB = (kwB == 0) ? -1 : 0;
                int posA = (ho + dhA + 1) * 17 + (wo + dwA + 1);
                int posB = (ho + dhB + 1) * 17 + (wo + dwB + 1);
                int idxA = ((paA * 2 + pbA) * 289 + posA) * 2 + ((lq & 1) ^ (posA & 1));
                int idxB = ((paB * 2 + pbB) * 289 + posB) * 2 + ((lq & 1) ^ (posB & 1));
                short8 b = H1[(lq < 2) ? idxA : idxB];
                acc = __builtin_amdgcn_mfma_f32_16x16x32_bf16(wf[p], b, acc, 0, 0, 0);
            }
            int pl  = (ho & 1) * 2 + (wo & 1);
            int pos = ((ho >> 1) + 1) * 9 + ((wo >> 1) + 1);
            int c8w = nt * 2 + (lq >> 1);
            int slot = (pl * 81 + pos) * 4 + (c8w ^ (pos & 3));
            __align__(8) bf16 ov[4];
            #pragma unroll
            for (int r = 0; r < 4; ++r) ov[r] = f2b(fmaxf(acc[r] + bv[r], 0.f));
            *reinterpret_cast<uint2*>(reinterpret_cast<char*>(&H2[slot]) + (lq & 1) * 8)
                = *reinterpret_cast<uint2*>(ov);
        }
    }
    __syncthreads();

    {
        const int nt = wv;
        short8 wf[9];
        #pragma unroll
        for (int t = 0; t < 9; ++t)
            wf[t] = *reinterpret_cast<const short8*>(wte3 + ((size_t)(t * 64 + nt * 16 + lp)) * 32 + lq * 8);
        float bv[4];
        #pragma unroll
        for (int r = 0; r < 4; ++r) bv[r] = eb3[nt * 16 + lq * 4 + r];

        bf16* yi = h3g + (size_t)img * 4096;
        for (int mt = 0; mt < 4; ++mt) {
            int m = mt * 16 + lp;
            int ho = m >> 3, wo = m & 7;
            f32x4 acc = {0.f, 0.f, 0.f, 0.f};
            #pragma unroll
            for (int t = 0; t < 9; ++t) {
                const int kh = t / 3, kw2 = t % 3;
                const int pa = (kh == 1) ? 0 : 1, dh = (kh == 0) ? -1 : 0;
                const int pb = (kw2 == 1) ? 0 : 1, dw = (kw2 == 0) ? -1 : 0;
                int pos = (ho + dh + 1) * 9 + (wo + dw + 1);
                int idx = ((pa * 2 + pb) * 81 + pos) * 4 + (lq ^ (pos & 3));
                acc = __builtin_amdgcn_mfma_f32_16x16x32_bf16(wf[t], H2[idx], acc, 0, 0, 0);
            }
            __align__(8) bf16 ov[4];
            #pragma unroll
            for (int r = 0; r < 4; ++r) ov[r] = f2b(fmaxf(acc[r] + bv[r], 0.f));
            *reinterpret_cast<uint2*>(yi + ((size_t)(ho * 8 + wo)) * 64 + nt * 16 + lq * 4)
                = *reinterpret_cast<uint2*>(ov);
        }
    }
}

// ============ FUSED dec1+dec2: h3b -> (LDS d1) -> d2p parity-plane layout ============
// d2p per image: [cls 4][nt 2][256 pos][16 ch] bf16 (32768 elem)
__global__ __launch_bounds__(256)
void dec12_fused(const bf16* __restrict__ h3g,
                 const bf16* __restrict__ wtb4, const float* __restrict__ db1,
                 const bf16* __restrict__ wtb5, const float* __restrict__ db2,
                 bf16* __restrict__ d2p)
{
    __shared__ short8 H3s[648];     // 9x9 padded x 8 c8
    __shared__ short8 D1s[2312];    // 17x17 padded x 8 c8
    const int img = blockIdx.x;
    const int tid = threadIdx.x;
    const bf16* xi = h3g + (size_t)img * 4096;

    for (int e = tid; e < 648; e += 256) {
        int c8 = e & 7, pos = e >> 3;
        int hl = pos / 9, wi = pos % 9;
        short8 v = s8zero();
        if (hl < 8 && wi < 8)
            v = *reinterpret_cast<const short8*>(xi + ((size_t)(hl * 8 + wi)) * 64 + c8 * 8);
        H3s[pos * 8 + (c8 ^ (pos & 7))] = v;
    }
    for (int e = tid; e < 264; e += 256) {
        int c8 = e & 7, q = e >> 3;
        int pos = (q < 17) ? (16 * 17 + q) : ((q - 17) * 17 + 16);
        D1s[pos * 8 + c8] = s8zero();
    }
    __syncthreads();

    const int wv = tid >> 6, lane = tid & 63;
    const int lp = lane & 15, lq = lane >> 4;

    // ---- dec1: 8x8x64 -> 16x16x64 into D1s ----
    {
        const int nt = wv;
        short8 wf[9][2];
        #pragma unroll
        for (int t = 0; t < 9; ++t) {
            const bf16* wp = wtb4 + ((size_t)t * 64 + nt * 16 + lp) * 64 + lq * 8;
            wf[t][0] = *reinterpret_cast<const short8*>(wp);
            wf[t][1] = *reinterpret_cast<const short8*>(wp + 32);
        }
        float bv[4];
        #pragma unroll
        for (int r = 0; r < 4; ++r) bv[r] = db1[nt * 16 + lq * 4 + r];

        const int c8w = nt * 2 + (lq >> 1);
        for (int mt = 0; mt < 4; ++mt) {
            int m = mt * 16 + lp;
            int hq = m >> 3, wq = m & 7;
            f32x4 zero = {0.f, 0.f, 0.f, 0.f};
            f32x4 acc[4] = {zero, zero, zero, zero};
            #pragma unroll
            for (int kh = 0; kh < 3; ++kh) {
                #pragma unroll
                for (int kw = 0; kw < 3; ++kw) {
                    const int pa = (kh + 1) & 1, pb = (kw + 1) & 1;
                    const int oh = (pa + 1 - kh) >> 1, ow = (pb + 1 - kw) >> 1;
                    const int cls = pa * 2 + pb;
                    const int t = kh * 3 + kw;
                    int pos = (hq + oh) * 9 + (wq + ow);
                    int sw = pos & 7;
                    acc[cls] = __builtin_amdgcn_mfma_f32_16x16x32_bf16(wf[t][0], H3s[pos * 8 + (lq ^ sw)], acc[cls], 0, 0, 0);
                    acc[cls] = __builtin_amdgcn_mfma_f32_16x16x32_bf16(wf[t][1], H3s[pos * 8 + ((4 + lq) ^ sw)], acc[cls], 0, 0, 0);
                }
            }
            #pragma unroll
            for (int cls = 0; cls < 4; ++cls) {
                int pa = cls >> 1, pb = cls & 1;
                int ho = hq * 2 + pa, wo = wq * 2 + pb;
                int pos = ho * 17 + wo;
                int slot = pos * 8 + (c8w ^ (pos & 7));
                __align__(8) bf16 ov[4];
                #pragma unroll
                for (int r = 0; r < 4; ++r) ov[r] = f2b(fmaxf(acc[cls][r] + bv[r], 0.f));
                *reinterpret_cast<uint2*>(reinterpret_cast<char*>(&D1s[slot]) + (lq & 1) * 8)
                    = *reinterpret_cast<uint2*>(ov);
            }
        }
    }
    __syncthreads();

    // ---- dec2: 16x16x64 -> 32x32x32, parity-plane coalesced write ----
    {
        const int nt = wv & 1;
        const int mt0 = (wv >> 1) * 8;
        short8 wf[9][2];
        #pragma unroll
        for (int t = 0; t < 9; ++t) {
            const bf16* wp = wtb5 + ((size_t)t * 32 + nt * 16 + lp) * 64 + lq * 8;
            wf[t][0] = *reinterpret_cast<const short8*>(wp);
            wf[t][1] = *reinterpret_cast<const short8*>(wp + 32);
        }
        float bv[4];
        #pragma unroll
        for (int r = 0; r < 4; ++r) bv[r] = db2[nt * 16 + lq * 4 + r];

        bf16* yo = d2p + (size_t)img * 32768;
        for (int mt = mt0; mt < mt0 + 8; ++mt) {
            const int hq = mt, wq = lp;
            f32x4 zero = {0.f, 0.f, 0.f, 0.f};
            f32x4 acc[4] = {zero, zero, zero, zero};
            #pragma unroll
            for (int kh = 0; kh < 3; ++kh) {
                #pragma unroll
                for (int kw = 0; kw < 3; ++kw) {
                    const int pa = (kh + 1) & 1, pb = (kw + 1) & 1;
                    const int oh = (pa + 1 - kh) >> 1, ow = (pb + 1 - kw) >> 1;
                    const int cls = pa * 2 + pb;
                    const int t = kh * 3 + kw;
                    int pos = (hq + oh) * 17 + (wq + ow);
                    int sw = pos & 7;
                    acc[cls] = __builtin_amdgcn_mfma_f32_16x16x32_bf16(wf[t][0], D1s[pos * 8 + (lq ^ sw)], acc[cls], 0, 0, 0);
                    acc[cls] = __builtin_amdgcn_mfma_f32_16x16x32_bf16(wf[t][1], D1s[pos * 8 + ((4 + lq) ^ sw)], acc[cls], 0, 0, 0);
                }
            }
            #pragma unroll
            for (int cls = 0; cls < 4; ++cls) {
                __align__(8) bf16 ov[4];
                #pragma unroll
                for (int r = 0; r < 4; ++r) ov[r] = f2b(fmaxf(acc[cls][r] + bv[r], 0.f));
                size_t off = (size_t)cls * 8192 + (size_t)nt * 4096 + (hq * 16 + wq) * 16 + lq * 4;
                *reinterpret_cast<uint2*>(yo + off) = *reinterpret_cast<uint2*>(ov);
            }
        }
    }
}

// ============ emb = sigmoid(h3b @ kwt^T + kb); n-tile via blockIdx.y ============
__global__ __launch_bounds__(256)
void emb_mfma(const bf16* __restrict__ h3b, const bf16* __restrict__ kwt,
              const float* __restrict__ kb, float* __restrict__ emb)
{
    __shared__ f32x4 Ls[3][64];
    const int imgbase = blockIdx.x * 16;
    const int nt = blockIdx.y;
    const int w = threadIdx.x >> 6, lane = threadIdx.x & 63;
    const int lp = lane & 15, lq = lane >> 4;
    const int k0 = w * 1024;

    f32x4 acc = {0.f, 0.f, 0.f, 0.f};
    const bf16* bp = h3b + (size_t)(imgbase + lp) * 4096 + k0 + lq * 8;
    const bf16* ap = kwt + (size_t)(nt * 16 + lp) * 4096 + k0 + lq * 8;
    for (int ks = 0; ks < 32; ++ks) {
        short8 bfrag = *reinterpret_cast<const short8*>(bp + ks * 32);
        short8 afrag = *reinterpret_cast<const short8*>(ap + ks * 32);
        acc = __builtin_amdgcn_mfma_f32_16x16x32_bf16(afrag, bfrag, acc, 0, 0, 0);
    }
    if (w > 0) Ls[w - 1][lane] = acc;
    __syncthreads();
    if (w == 0) {
        #pragma unroll
        for (int ww = 0; ww < 3; ++ww) acc += Ls[ww][lane];
        const int e0 = nt * 16 + lq * 4;
        #pragma unroll
        for (int r = 0; r < 4; ++r) {
            int e = e0 + r;
            if (e < 110) {
                float v = acc[r] + kb[e];
                emb[(size_t)(imgbase + lp) * 110 + e] = 1.f / (1.f + expf(-v));
            }
        }
    }
}

// ============ dec3: d2p (parity layout) -> conv_t1 -> fused 1x1 -> dec fp32 NCHW ============
__global__ __launch_bounds__(256)
void convt1_mfma_fused(const bf16* __restrict__ d2p, const bf16* __restrict__ wtb,
                       const float* __restrict__ bias,
                       const float* __restrict__ w4, const float* __restrict__ b4,
                       float* __restrict__ dec)
{
    constexpr int C8 = 4;
    constexpr int HR = 18, WR = 34, NPOS = HR * WR;
    __shared__ short8 Xs[NPOS * C8];

    const int img  = blockIdx.x >> 1;
    const int half = blockIdx.x & 1;
    const int hbase = half * 16;
    const bf16* xi = d2p + (size_t)img * 32768;

    for (int e = threadIdx.x; e < NPOS * C8; e += 256) {
        int c8 = e & 3, pos = e >> 2;
        int hr = pos / WR, wr = pos % WR;
        int hi = hbase - 1 + hr, wi = wr - 1;
        short8 v = s8zero();
        if ((unsigned)hi < 32u && (unsigned)wi < 32u) {
            int cls = ((hi & 1) << 1) | (wi & 1);
            size_t src = (size_t)cls * 8192 + (size_t)(c8 >> 1) * 4096
                       + (((hi >> 1) << 4) + (wi >> 1)) * 16 + (c8 & 1) * 8;
            v = *reinterpret_cast<const short8*>(xi + src);
        }
        Xs[pos * C8 + (c8 ^ (pos & 3))] = v;
    }
    __syncthreads();

    const int wv = threadIdx.x >> 6, lane = threadIdx.x & 63;
    const int lp = lane & 15, lq = lane >> 4;

    short8 wf[9];
    #pragma unroll
    for (int t = 0; t < 9; ++t)
        wf[t] = *reinterpret_cast<const short8*>(wtb + ((size_t)t * 16 + lp) * 32 + lq * 8);
    float bv[4];
    #pragma unroll
    for (int r = 0; r < 4; ++r) bv[r] = bias[lq * 4 + r];
    float w4r[3][4];
    #pragma unroll
    for (int j = 0; j < 3; ++j)
        #pragma unroll
        for (int r = 0; r < 4; ++r) w4r[j][r] = w4[j * 16 + lq * 4 + r];
    float b4r[3] = {b4[0], b4[1], b4[2]};

    for (int mt = wv; mt < 32; mt += 4) {
        int m = mt * 16 + lp;
        int hol = m >> 5, wo = m & 31;
        f32x4 acc = {0.f, 0.f, 0.f, 0.f};
        #pragma unroll
        for (int t = 0; t < 9; ++t) {
            int kh = t / 3, kw = t % 3;
            int pos = (hol + 2 - kh) * WR + (wo + 2 - kw);
            short8 b0 = Xs[pos * C8 + (lq ^ (pos & 3))];
            acc = __builtin_amdgcn_mfma_f32_16x16x32_bf16(wf[t], b0, acc, 0, 0, 0);
        }
        float s0 = 0.f, s1 = 0.f, s2 = 0.f;
        #pragma unroll
        for (int r = 0; r < 4; ++r) {
            float v = fmaxf(acc[r] + bv[r], 0.f);
            s0 += v * w4r[0][r]; s1 += v * w4r[1][r]; s2 += v * w4r[2][r];
        }
        s0 += __shfl_xor(s0, 16); s0 += __shfl_xor(s0, 32);
        s1 += __shfl_xor(s1, 16); s1 += __shfl_xor(s1, 32);
        s2 += __shfl_xor(s2, 16); s2 += __shfl_xor(s2, 32);
        if (lq == 0) {
            int ho = hbase + hol;
            size_t base = (size_t)img * 3072 + ho * 32 + wo;
            dec[base]        = s0 + b4r[0];
            dec[base + 1024] = s1 + b4r[1];
            dec[base + 2048] = s2 + b4r[2];
        }
    }
}

// ============ KDE: 64 blocks -> fdb bf16 [64][1280] (padded) ============
__global__ __launch_bounds__(256)
void kde_kernel(const float* __restrict__ emb, bf16* __restrict__ fdb)
{
    __shared__ float es[3520];
    const int b = blockIdx.x, tid = threadIdx.x;
    for (int i = tid; i < 3520; i += 256) es[i] = emb[(size_t)b * 3520 + i];
    __syncthreads();
    if (tid < 110) {
        float dens[11];
        #pragma unroll
        for (int j = 0; j < 11; ++j) dens[j] = 0.f;
        for (int n = 0; n < 32; ++n) {
            float e = es[n * 110 + tid];
            #pragma unroll
            for (int j = 0; j < 11; ++j) {
                float d = 0.1f * j - e;
                dens[j] += __expf(-50.f * d * d);
            }
        }
        float s = 0.f;
        #pragma unroll
        for (int j = 0; j < 11; ++j) s += dens[j];
        float inv = 1.f / s;
        #pragma unroll
        for (int j = 0; j < 11; ++j)
            fdb[(size_t)b * 1280 + tid * 11 + j] = f2b(dens[j] * inv);
    } else if (tid >= 128 && tid < 198) {
        fdb[(size_t)b * 1280 + 1210 + (tid - 128)] = f2b(0.f);
    }
}

// ============ dense MFMA layer ============
template<int K, int N, int RELU>
__global__ __launch_bounds__(256)
void dense_mfma(const bf16* __restrict__ inb, const bf16* __restrict__ wtb,
                const float* __restrict__ bias, bf16* __restrict__ outb)
{
    __shared__ f32x4 Ls[3][64];
    constexpr int KW = K / 4;
    const int mt = blockIdx.x, nt = blockIdx.y;
    const int w = threadIdx.x >> 6, lane = threadIdx.x & 63;
    const int lp = lane & 15, lq = lane >> 4;
    const int k0 = w * KW;

    f32x4 acc = {0.f, 0.f, 0.f, 0.f};
    const bf16* bp = inb + (size_t)(mt * 16 + lp) * K + k0 + lq * 8;
    const bf16* ap = wtb + (size_t)(nt * 16 + lp) * K + k0 + lq * 8;
    for (int ks = 0; ks < KW / 32; ++ks) {
        short8 bfrag = *reinterpret_cast<const short8*>(bp + ks * 32);
        short8 afrag = *reinterpret_cast<const short8*>(ap + ks * 32);
        acc = __builtin_amdgcn_mfma_f32_16x16x32_bf16(afrag, bfrag, acc, 0, 0, 0);
    }
    if (w > 0) Ls[w - 1][lane] = acc;
    __syncthreads();
    if (w == 0) {
        #pragma unroll
        for (int ww = 0; ww < 3; ++ww) acc += Ls[ww][lane];
        const int b = mt * 16 + lp;
        const int o0 = nt * 16 + lq * 4;
        __align__(8) bf16 ov[4];
        #pragma unroll
        for (int r = 0; r < 4; ++r) {
            float v = acc[r] + bias[o0 + r];
            if (RELU) v = fmaxf(v, 0.f);
            ov[r] = f2b(v);
        }
        *reinterpret_cast<uint2*>(outb + (size_t)b * N + o0) = *reinterpret_cast<uint2*>(ov);
    }
}

// ============ f3: 256 -> 4, one block ============
__global__ __launch_bounds__(256)
void f3_kernel(const bf16* __restrict__ m2b, const float* __restrict__ f3w,
               const float* __restrict__ f3b, float* __restrict__ logits)
{
    __shared__ float m2s[64 * 256];
    const int tid = threadIdx.x;
    for (int i = tid; i < 16384; i += 256) m2s[i] = __bfloat162float(m2b[i]);
    __syncthreads();
    int b = tid >> 2, o = tid & 3;
    float a = f3b[o];
    const float* wr = f3w + o * 256;
    for (int k = 0; k < 256; ++k) a += m2s[b * 256 + k] * wr[k];
    logits[b * 4 + o] = a;
}

extern "C" void kernel_launch(void* const* d_in, const int* in_sizes, int n_in,
                              void* d_out, int out_size, void* d_ws, size_t ws_size,
                              hipStream_t stream)
{
    const float* x    = (const float*)d_in[0];
    const float* ew1  = (const float*)d_in[1];
    const float* eb1  = (const float*)d_in[2];
    const float* ew2  = (const float*)d_in[3];
    const float* eb2  = (const float*)d_in[4];
    const float* ew3  = (const float*)d_in[5];
    const float* eb3  = (const float*)d_in[6];
    const float* kw   = (const float*)d_in[7];
    const float* kb   = (const float*)d_in[8];
    const float* dw1  = (const float*)d_in[9];
    const float* db1  = (const float*)d_in[10];
    const float* dw2  = (const float*)d_in[11];
    const float* db2  = (const float*)d_in[12];
    const float* dw3  = (const float*)d_in[13];
    const float* db3  = (const float*)d_in[14];
    const float* dw4  = (const float*)d_in[15];
    const float* db4  = (const float*)d_in[16];
    const float* f1w  = (const float*)d_in[17];
    const float* f1b  = (const float*)d_in[18];
    const float* f2w  = (const float*)d_in[19];
    const float* f2b_ = (const float*)d_in[20];
    const float* f3w  = (const float*)d_in[21];
    const float* f3b  = (const float*)d_in[22];

    // ---------- workspace ----------
    char* ws = (char*)d_ws;
    float* emb  = (float*)(ws + 0);          //   901,120
    bf16*  fdb  = (bf16*) (ws + 901120);     //   163,840
    bf16*  m1b  = (bf16*) (ws + 1064960);    //    65,536
    bf16*  m2b  = (bf16*) (ws + 1130496);    //    32,768
    bf16*  wte1 = (bf16*) (ws + 1163264);    //     3,072
    bf16*  wte2 = (bf16*) (ws + 1166336);    //    10,240
    bf16*  wte3 = (bf16*) (ws + 1176576);    //    36,864
    bf16*  wtb4 = (bf16*) (ws + 1213440);    //    73,728
    bf16*  wtb5 = (bf16*) (ws + 1287168);    //    36,864
    bf16*  wtb6 = (bf16*) (ws + 1324032);    //     9,216
    bf16*  kwt  = (bf16*) (ws + 1333248);    //   917,504
    bf16*  wtf1 = (bf16*) (ws + 2250752);    // 1,310,720
    bf16*  wtf2 = (bf16*) (ws + 3561472);    //   262,144
    const size_t FIXED = 3823616;

    // per image: h3b 8 KB + d2p 64 KB
    const size_t PER_IMG = 73728;
    int CHUNK = 2048;
    while (CHUNK > 16 && FIXED + (size_t)CHUNK * PER_IMG > ws_size) CHUNK >>= 1;
    const int NCHUNK = 2048 / CHUNK;

    char* p   = ws + FIXED;
    bf16* h3b = (bf16*)(p);
    bf16* d2p = (bf16*)(p + (size_t)CHUNK * 8192);

    float* logits = (float*)d_out;            // 64*4
    float* dec    = (float*)d_out + 256;      // 2048*3*32*32 NCHW

    // ---- fused weight prep (1 launch) ----
    prep_weights<<<(1330176 + 255)/256, 256, 0, stream>>>(
        ew1, ew2, ew3, dw1, dw2, dw3, kw, f1w, f2w,
        wte1, wte2, wte3, wtb4, wtb5, wtb6, kwt, wtf1, wtf2);

    for (int c = 0; c < NCHUNK; ++c) {
        const float* xc   = x   + (size_t)c * CHUNK * 3 * 1024;
        float*       decc = dec + (size_t)c * CHUNK * 3 * 1024;
        float*       embc = emb + (size_t)c * CHUNK * 110;

        enc123_fused<<<CHUNK, 256, 0, stream>>>(xc, wte1, eb1, wte2, eb2, wte3, eb3, h3b);
        emb_mfma<<<dim3(CHUNK/16, 7), 256, 0, stream>>>(h3b, kwt, kb, embc);
        dec12_fused<<<CHUNK, 256, 0, stream>>>(h3b, wtb4, db1, wtb5, db2, d2p);
        convt1_mfma_fused<<<CHUNK*2, 256, 0, stream>>>(d2p, wtb6, db3, dw4, db4, decc);
    }

    // classifier: KDE -> f1 (MFMA) -> f2 (MFMA) -> f3
    kde_kernel<<<64, 256, 0, stream>>>(emb, fdb);
    dense_mfma<1280, 512, 1><<<dim3(4, 32), 256, 0, stream>>>(fdb, wtf1, f1b, m1b);
    dense_mfma<512, 256, 1> <<<dim3(4, 16), 256, 0, stream>>>(m1b, wtf2, f2b_, m2b);
    f3_kernel<<<1, 256, 0, stream>>>(m2b, f3w, f3b, logits);
}